// Round 4
// baseline (913.292 us; speedup 1.0000x reference)
//
#include <hip/hip_runtime.h>

// GGNN on MI355X.
// Pipeline: [precompute_swt -> big_mm -> gating] x2; step-2 gating fuses the
// output head. All heavy math in bf16 MFMA (16x16x32), accumulate f32.
// A (256 MB f32) is the dominant HBM stream, read once per propagate step.
// R2: big_mm K-split x2, gating col-split x4 -> NEUTRAL (531->549 us).
// R4: MEASUREMENT ROUND. big_mm body repeated 4x per dispatch (reps 0-2 ->
//     dump, rep 3 -> real outputs) to push it past the 150us top-5 cutoff
//     so rocprof shows its FETCH_SIZE/hbm_gbps/MfmaUtil/VALUBusy/VGPRs.
//     Also reverted nontemporal loads (R1 confound).

typedef float  f32x4_t  __attribute__((ext_vector_type(4)));
typedef __bf16 bf16x8_t __attribute__((ext_vector_type(8)));
typedef __bf16 bf16x4_t __attribute__((ext_vector_type(4)));

#define MFMA16(a, b, c) __builtin_amdgcn_mfma_f32_16x16x32_bf16((a), (b), (c), 0, 0, 0)

static constexpr int kB  = 8;
static constexpr int kN  = 1000;
static constexpr int kD  = 64;
static constexpr int kAD = 32;
static constexpr int kNE = 4000;          // N*E
static constexpr int kBN = 8000;          // B*N (total rows)
static constexpr int kP  = kBN * kD;      // floats per partial buffer (512000)

__device__ __forceinline__ float4 ld4(const float* p) {
    return *reinterpret_cast<const float4*>(p);
}

__device__ __forceinline__ bf16x8_t cvt8(float4 a, float4 b) {
    bf16x8_t r;
    r[0] = (__bf16)a.x; r[1] = (__bf16)a.y; r[2] = (__bf16)a.z; r[3] = (__bf16)a.w;
    r[4] = (__bf16)b.x; r[5] = (__bf16)b.y; r[6] = (__bf16)b.z; r[7] = (__bf16)b.w;
    return r;
}

// bf16x8 of (p0[i] + p1[i]) for i in 0..7 — partial-sum merge
__device__ __forceinline__ bf16x8_t sum8(const float* p0, const float* p1) {
    const float4 a0 = ld4(p0), a1 = ld4(p0 + 4);
    const float4 b0 = ld4(p1), b1 = ld4(p1 + 4);
    bf16x8_t r;
    r[0] = (__bf16)(a0.x + b0.x); r[1] = (__bf16)(a0.y + b0.y);
    r[2] = (__bf16)(a0.z + b0.z); r[3] = (__bf16)(a0.w + b0.w);
    r[4] = (__bf16)(a1.x + b1.x); r[5] = (__bf16)(a1.y + b1.y);
    r[6] = (__bf16)(a1.z + b1.z); r[7] = (__bf16)(a1.w + b1.w);
    return r;
}

__device__ __forceinline__ float sigm(float x) {
    x = fminf(fmaxf(x, -30.f), 30.f);
    return 1.0f / (1.0f + __expf(-x));
}

__device__ __forceinline__ float fast_tanh(float x) {
    x = fminf(fmaxf(x, -15.f), 15.f);
    const float e = __expf(-2.0f * x);
    return (1.0f - e) / (1.0f + e);
}

// ---------------------------------------------------------------------------
// SWT[(b*2+h)*64 + f][j] (bf16, j = e*1000 + jj, row stride kNE) =
//   sum_d state[b][jj][d] * W[e][f][d]   with W = (h ? W_out : W_in)
// ---------------------------------------------------------------------------
__global__ __launch_bounds__(256) void precompute_swt(
    const float* __restrict__ state,   // [8000][64]
    const float* __restrict__ W_in,    // [4][64][64]
    const float* __restrict__ W_out,
    __bf16* __restrict__ SWT)
{
    const int bx = blockIdx.x;
    const int jt = bx & 15;
    const int e  = (bx >> 4) & 3;
    const int h  = (bx >> 6) & 1;
    const int b  = bx >> 7;
    const float* W = (h ? W_out : W_in) + e * kD * kD;

    const int tid  = threadIdx.x;
    const int w    = tid >> 6;
    const int lane = tid & 63;
    const int m    = lane & 15;
    const int q    = lane >> 4;

    __shared__ __bf16 T[64][72];  // [f][j_local], +8 pad vs bank conflicts

    const int  jj    = jt * 64 + w * 16 + m;
    const bool valid = (jj < kN);
    const float* srow = state + ((size_t)b * kN + (valid ? jj : kN - 1)) * kD + q * 8;
    float4 a0 = ld4(srow),      a1 = ld4(srow + 4);
    float4 a2 = ld4(srow + 32), a3 = ld4(srow + 36);
    if (!valid) {
        a0 = make_float4(0.f, 0.f, 0.f, 0.f); a1 = a0; a2 = a0; a3 = a0;
    }
    const bf16x8_t af0 = cvt8(a0, a1);
    const bf16x8_t af1 = cvt8(a2, a3);

    #pragma unroll
    for (int c = 0; c < 4; ++c) {
        const int f = c * 16 + m;
        const float* wrow = W + f * kD + q * 8;
        const bf16x8_t bf0 = cvt8(ld4(wrow),      ld4(wrow + 4));
        const bf16x8_t bf1 = cvt8(ld4(wrow + 32), ld4(wrow + 36));
        f32x4_t acc = {0.f, 0.f, 0.f, 0.f};
        acc = MFMA16(af0, bf0, acc);
        acc = MFMA16(af1, bf1, acc);
        const int j0 = w * 16 + q * 4;
        bf16x4_t v;
        v[0] = (__bf16)acc[0]; v[1] = (__bf16)acc[1];
        v[2] = (__bf16)acc[2]; v[3] = (__bf16)acc[3];
        *reinterpret_cast<bf16x4_t*>(&T[f][j0]) = v;
    }
    __syncthreads();

    const size_t rowbase = (size_t)((b * 2 + h) * kD);
    #pragma unroll
    for (int rep = 0; rep < 2; ++rep) {
        const int cc = tid + rep * 256;       // 0..511
        const int f  = cc >> 3;
        const int ch = cc & 7;
        const int jj0 = jt * 64 + ch * 8;
        if (jj0 < kN) {
            const uint4 v = *reinterpret_cast<uint4*>(&T[f][ch * 8]);
            *reinterpret_cast<uint4*>(SWT + (rowbase + f) * kNE + e * kN + jj0) = v;
        }
    }
}

// ---------------------------------------------------------------------------
// a_half_p[ks][b][i][f] = sum_{j in Kslice(ks)} A[b][i][h*4000+j] * SWT[...][j]
// grid: 512 = 16 tiles x 2 h x 8 b x 2 ks; block 256 (4 waves x 16 rows).
// R4 PROBE: whole body executed kReps=4 times; reps 0..2 write to `dump`,
// rep 3 writes real outputs. Identical work every call (graph-safe).
// ---------------------------------------------------------------------------
static constexpr int kReps = 4;

__global__ __launch_bounds__(256, 2) void big_mm(
    const float* __restrict__ A,        // [8][1000][8000]
    const __bf16* __restrict__ SWT,     // [16*64][4000]
    float* __restrict__ a_in_p,         // [2][8000][64]
    float* __restrict__ a_out_p,
    float* __restrict__ dump)           // [2][8000][64]-shaped scratch
{
    const int bx   = blockIdx.x;
    const int tile = bx & 15;
    const int h    = (bx >> 4) & 1;
    const int b    = (bx >> 5) & 7;
    const int ks   = (bx >> 8) & 1;
    const int tid  = threadIdx.x;
    const int w    = tid >> 6;
    const int lane = tid & 63;
    const int m    = lane & 15;
    const int q    = lane >> 4;

    const int row  = tile * 64 + w * 16 + m;
    const int rowc = row < kN ? row : kN - 1;
    const int kbeg = ks * 1984;

    const float*  Ap = A + ((size_t)b * kN + rowc) * (2 * kNE) + h * kNE + kbeg + q * 8;
    const __bf16* SW = SWT + ((size_t)(b * 2 + h) * kD) * kNE + kbeg + q * 8;
    const __bf16* SB0 = SW + (size_t)(0 * 16 + m) * kNE;
    const __bf16* SB1 = SW + (size_t)(1 * 16 + m) * kNE;
    const __bf16* SB2 = SW + (size_t)(2 * 16 + m) * kNE;
    const __bf16* SB3 = SW + (size_t)(3 * 16 + m) * kNE;

    #pragma unroll 1
    for (int rep = 0; rep < kReps; ++rep) {
        f32x4_t acc0 = {0.f, 0.f, 0.f, 0.f};
        f32x4_t acc1 = {0.f, 0.f, 0.f, 0.f};
        f32x4_t acc2 = {0.f, 0.f, 0.f, 0.f};
        f32x4_t acc3 = {0.f, 0.f, 0.f, 0.f};

        // prologue: relative k = 0 (both 32-halves)
        bf16x8_t ca0 = cvt8(ld4(Ap + 0),  ld4(Ap + 4));
        bf16x8_t ca1 = cvt8(ld4(Ap + 32), ld4(Ap + 36));
        bf16x8_t cb00 = *(const bf16x8_t*)(SB0);
        bf16x8_t cb01 = *(const bf16x8_t*)(SB1);
        bf16x8_t cb02 = *(const bf16x8_t*)(SB2);
        bf16x8_t cb03 = *(const bf16x8_t*)(SB3);
        bf16x8_t cb10 = *(const bf16x8_t*)(SB0 + 32);
        bf16x8_t cb11 = *(const bf16x8_t*)(SB1 + 32);
        bf16x8_t cb12 = *(const bf16x8_t*)(SB2 + 32);
        bf16x8_t cb13 = *(const bf16x8_t*)(SB3 + 32);

        // 31 full 64-wide iterations; ks=1 adds a 32-wide tail afterwards.
        for (int kk = 0; kk < 31; ++kk) {
            const int kn = (kk + 1) * 64;
            const int k2 = (kk < 30) ? (kn + 32) : 0;

            const float4 x0 = ld4(Ap + kn),  x1 = ld4(Ap + kn + 4);
            const float4 x2 = ld4(Ap + k2),  x3 = ld4(Ap + k2 + 4);
            const bf16x8_t nb00 = *(const bf16x8_t*)(SB0 + kn);
            const bf16x8_t nb01 = *(const bf16x8_t*)(SB1 + kn);
            const bf16x8_t nb02 = *(const bf16x8_t*)(SB2 + kn);
            const bf16x8_t nb03 = *(const bf16x8_t*)(SB3 + kn);
            const bf16x8_t nb10 = *(const bf16x8_t*)(SB0 + k2);
            const bf16x8_t nb11 = *(const bf16x8_t*)(SB1 + k2);
            const bf16x8_t nb12 = *(const bf16x8_t*)(SB2 + k2);
            const bf16x8_t nb13 = *(const bf16x8_t*)(SB3 + k2);

            acc0 = MFMA16(ca0, cb00, acc0);
            acc1 = MFMA16(ca0, cb01, acc1);
            acc2 = MFMA16(ca0, cb02, acc2);
            acc3 = MFMA16(ca0, cb03, acc3);
            acc0 = MFMA16(ca1, cb10, acc0);
            acc1 = MFMA16(ca1, cb11, acc1);
            acc2 = MFMA16(ca1, cb12, acc2);
            acc3 = MFMA16(ca1, cb13, acc3);

            ca0 = cvt8(x0, x1);
            ca1 = cvt8(x2, x3);
            cb00 = nb00; cb01 = nb01; cb02 = nb02; cb03 = nb03;
            cb10 = nb10; cb11 = nb11; cb12 = nb12; cb13 = nb13;
        }
        if (ks == 1) {  // tail: k = 3968, 32 wide (first half only)
            acc0 = MFMA16(ca0, cb00, acc0);
            acc1 = MFMA16(ca0, cb01, acc1);
            acc2 = MFMA16(ca0, cb02, acc2);
            acc3 = MFMA16(ca0, cb03, acc3);
        }

        float* base = (rep < kReps - 1)
                        ? (dump    + (h ? kP * 2 : 0))
                        : ((h ? a_out_p : a_in_p));
        float* dst = base + (size_t)ks * kP + (size_t)b * kN * kD;
        const int i0 = tile * 64 + w * 16 + q * 4;
        #pragma unroll
        for (int r = 0; r < 4; ++r) {
            const int i = i0 + r;
            if (i < kN) {
                float* drow = dst + (size_t)i * kD + m;
                drow[0]  = acc0[r];
                drow[16] = acc1[r];
                drow[32] = acc2[r];
                drow[48] = acc3[r];
            }
        }
    }
}

// ---------------------------------------------------------------------------
// Gating, col-split: block = 256 (4 waves), 16 rows per block, wave c owns
// output cols f = c*16..c*16+15.
// ---------------------------------------------------------------------------
__global__ __launch_bounds__(256, 2) void gating(
    const float* __restrict__ a_in_p,   // [2][8000][64]
    const float* __restrict__ a_out_p,
    const float* __restrict__ state,
    const float* __restrict__ W_r,
    const float* __restrict__ W_z,
    const float* __restrict__ W_h,
    float* __restrict__ s_next,
    const float* __restrict__ ann,
    const float* __restrict__ Wo1,
    const float* __restrict__ Wo2,
    float* __restrict__ out,
    const int step)
{
    const int i0   = blockIdx.x * 16;
    const int tid  = threadIdx.x;
    const int c    = tid >> 6;           // wave = column slice
    const int lane = tid & 63;
    const int m    = lane & 15;
    const int q    = lane >> 4;
    const int f    = c * 16 + m;

    __shared__ __bf16 TL[16][72];
    __shared__ float  Osum[4][16];

    const size_t rowA = (size_t)(i0 + m);

    bf16x8_t xf[6];
    {
        const float* p = a_in_p + rowA * kD + q * 8;
        xf[0] = sum8(p,      p + kP);
        xf[1] = sum8(p + 32, p + 32 + kP);
        p = a_out_p + rowA * kD + q * 8;
        xf[2] = sum8(p,      p + kP);
        xf[3] = sum8(p + 32, p + 32 + kP);
        p = state + rowA * kD + q * 8;
        xf[4] = cvt8(ld4(p),      ld4(p + 4));
        xf[5] = cvt8(ld4(p + 32), ld4(p + 36));
    }

    f32x4_t accr = {0.f, 0.f, 0.f, 0.f};
    f32x4_t accz = {0.f, 0.f, 0.f, 0.f};
    f32x4_t acch = {0.f, 0.f, 0.f, 0.f};

    const float* wr = W_r + f * 192 + q * 8;
    const float* wz = W_z + f * 192 + q * 8;
    const float* wh = W_h + f * 192 + q * 8;
    #pragma unroll
    for (int kc = 0; kc < 6; ++kc) {
        accr = MFMA16(xf[kc], cvt8(ld4(wr + kc * 32), ld4(wr + kc * 32 + 4)), accr);
        accz = MFMA16(xf[kc], cvt8(ld4(wz + kc * 32), ld4(wz + kc * 32 + 4)), accz);
        if (kc < 4)  // h-preact uses only [a_in|a_out] here (K=128)
            acch = MFMA16(xf[kc], cvt8(ld4(wh + kc * 32), ld4(wh + kc * 32 + 4)), acch);
    }

    float sC[4];
    #pragma unroll
    for (int r = 0; r < 4; ++r)
        sC[r] = state[(size_t)(i0 + q * 4 + r) * kD + f];

    // rs = sigm(r_pre) * state -> LDS transpose (C layout -> A layout)
    #pragma unroll
    for (int r = 0; r < 4; ++r)
        TL[q * 4 + r][f] = (__bf16)(sigm(accr[r]) * sC[r]);
    __syncthreads();
    const bf16x8_t rs0 = *(const bf16x8_t*)&TL[m][q * 8];
    const bf16x8_t rs1 = *(const bf16x8_t*)&TL[m][32 + q * 8];

    const float* wh3 = W_h + f * 192 + 128 + q * 8;
    acch = MFMA16(rs0, cvt8(ld4(wh3),      ld4(wh3 + 4)),  acch);
    acch = MFMA16(rs1, cvt8(ld4(wh3 + 32), ld4(wh3 + 36)), acch);

    float ns[4];
    #pragma unroll
    for (int r = 0; r < 4; ++r) {
        const float zv = sigm(accz[r]);
        ns[r] = (1.f - zv) * sC[r] + zv * fast_tanh(acch[r]);
    }

    if (step == 1) {
        #pragma unroll
        for (int r = 0; r < 4; ++r)
            s_next[(size_t)(i0 + q * 4 + r) * kD + f] = ns[r];
    } else {
        __syncthreads();  // all waves done reading rs frags from TL
        #pragma unroll
        for (int r = 0; r < 4; ++r)
            TL[q * 4 + r][f] = (__bf16)ns[r];
        __syncthreads();
        const bf16x8_t j0 = *(const bf16x8_t*)&TL[m][q * 8];
        const bf16x8_t j1 = *(const bf16x8_t*)&TL[m][32 + q * 8];
        const float* ap = ann + rowA * kAD + q * 8;
        const bf16x8_t j2 = cvt8(ld4(ap), ld4(ap + 4));

        f32x4_t acco = {0.f, 0.f, 0.f, 0.f};
        const float* wo = Wo1 + (size_t)f * 96 + q * 8;
        acco = MFMA16(j0, cvt8(ld4(wo),      ld4(wo + 4)),  acco);
        acco = MFMA16(j1, cvt8(ld4(wo + 32), ld4(wo + 36)), acco);
        acco = MFMA16(j2, cvt8(ld4(wo + 64), ld4(wo + 68)), acco);

        const float w2 = Wo2[f];
        float vs[4];
        #pragma unroll
        for (int r = 0; r < 4; ++r)
            vs[r] = fast_tanh(acco[r]) * w2;
        #pragma unroll
        for (int off = 1; off <= 8; off <<= 1) {
            #pragma unroll
            for (int r = 0; r < 4; ++r)
                vs[r] += __shfl_xor(vs[r], off, 64);
        }
        if (m == 0) {
            #pragma unroll
            for (int r = 0; r < 4; ++r)
                Osum[c][q * 4 + r] = vs[r];
        }
        __syncthreads();
        if (tid < 16)
            out[i0 + tid] = Osum[0][tid] + Osum[1][tid] + Osum[2][tid] + Osum[3][tid];
    }
}

extern "C" void kernel_launch(void* const* d_in, const int* in_sizes, int n_in,
                              void* d_out, int out_size, void* d_ws, size_t ws_size,
                              hipStream_t stream) {
    (void)in_sizes; (void)n_in; (void)out_size; (void)ws_size;

    const float* prop_state = (const float*)d_in[0];
    const float* annotation = (const float*)d_in[1];
    const float* A          = (const float*)d_in[2];
    const float* W_in       = (const float*)d_in[3];
    const float* W_out      = (const float*)d_in[4];
    const float* W_r        = (const float*)d_in[5];
    const float* W_z        = (const float*)d_in[6];
    const float* W_h        = (const float*)d_in[7];
    const float* Wo1        = (const float*)d_in[8];
    const float* Wo2        = (const float*)d_in[9];
    float* out = (float*)d_out;

    char* ws = (char*)d_ws;
    __bf16* SWT    = (__bf16*)(ws);                 // 8,192,000 B
    float*  a_in_p = (float*)(ws + 8192000);        // 2 x 2,048,000 B
    float*  a_out_p= (float*)(ws + 12288000);       // 2 x 2,048,000 B
    float*  s1     = (float*)(ws + 16384000);       // 2,048,000 B
    float*  dump   = (float*)(ws + 33554432);       // probe dump, 8 MB zone

    // step 1
    precompute_swt<<<1024, 256, 0, stream>>>(prop_state, W_in, W_out, SWT);
    big_mm<<<512, 256, 0, stream>>>(A, SWT, a_in_p, a_out_p, dump);
    gating<<<500, 256, 0, stream>>>(a_in_p, a_out_p, prop_state, W_r, W_z, W_h,
                                    s1, nullptr, nullptr, nullptr, nullptr, 1);
    // step 2 (+ fused output head)
    precompute_swt<<<1024, 256, 0, stream>>>(s1, W_in, W_out, SWT);
    big_mm<<<512, 256, 0, stream>>>(A, SWT, a_in_p, a_out_p, dump);
    gating<<<500, 256, 0, stream>>>(a_in_p, a_out_p, s1, W_r, W_z, W_h,
                                    nullptr, annotation, Wo1, Wo2, out, 2);
}

// Round 5
// 514.879 us; speedup vs baseline: 1.7738x; 1.7738x over previous
//
#include <hip/hip_runtime.h>

// GGNN on MI355X.
// R4 finding: old big_mm was transaction-bound (hbm 2.2 TB/s, MfmaUtil 4%,
// VALUBusy 4.6%, Occ 19%): every load = 16 scattered 128B segments because
// MFMA fragment rows live in different lanes. ~340 us of dur_us is harness
// floor (1GB ws poison fills + input restore) — untouchable.
// R5: all hot global accesses made lane-contiguous:
//   relayout_A: A f32 -> Afrag bf16 in MFMA A-fragment order (LDS transpose,
//               copy-class traffic 387 MB).
//   precompute_swt: writes SWT directly in B-fragment order.
//   big_mm_f: barrier-free, LDS-free; per k-step 5 contiguous 1KB loads +
//             4 MFMA; 4 k-splits -> 1024 blocks (16 waves/CU).
//   gating: sums 4 K-partials; step-2 fuses output head.

typedef float  f32x4_t  __attribute__((ext_vector_type(4)));
typedef __bf16 bf16x8_t __attribute__((ext_vector_type(8)));
typedef __bf16 bf16x4_t __attribute__((ext_vector_type(4)));

#define MFMA16(a, b, c) __builtin_amdgcn_mfma_f32_16x16x32_bf16((a), (b), (c), 0, 0, 0)

static constexpr int kN     = 1000;
static constexpr int kD     = 64;
static constexpr int kAD    = 32;
static constexpr int kNE    = 4000;           // N*E (K per h-half)
static constexpr int kSteps = 125;            // kNE / 32
static constexpr int kP     = 8000 * 64;      // floats per partial plane

__device__ __forceinline__ float4 ld4(const float* p) {
    return *reinterpret_cast<const float4*>(p);
}

__device__ __forceinline__ bf16x8_t cvt8(float4 a, float4 b) {
    bf16x8_t r;
    r[0] = (__bf16)a.x; r[1] = (__bf16)a.y; r[2] = (__bf16)a.z; r[3] = (__bf16)a.w;
    r[4] = (__bf16)b.x; r[5] = (__bf16)b.y; r[6] = (__bf16)b.z; r[7] = (__bf16)b.w;
    return r;
}

// bf16x8 of sum over 4 partial planes at stride kP
__device__ __forceinline__ bf16x8_t sum4p(const float* p) {
    float s0 = 0.f, s1 = 0.f, s2 = 0.f, s3 = 0.f;
    float s4 = 0.f, s5 = 0.f, s6 = 0.f, s7 = 0.f;
    #pragma unroll
    for (int pl = 0; pl < 4; ++pl) {
        const float4 a0 = ld4(p + (size_t)pl * kP);
        const float4 a1 = ld4(p + (size_t)pl * kP + 4);
        s0 += a0.x; s1 += a0.y; s2 += a0.z; s3 += a0.w;
        s4 += a1.x; s5 += a1.y; s6 += a1.z; s7 += a1.w;
    }
    bf16x8_t r;
    r[0] = (__bf16)s0; r[1] = (__bf16)s1; r[2] = (__bf16)s2; r[3] = (__bf16)s3;
    r[4] = (__bf16)s4; r[5] = (__bf16)s5; r[6] = (__bf16)s6; r[7] = (__bf16)s7;
    return r;
}

__device__ __forceinline__ float sigm(float x) {
    x = fminf(fmaxf(x, -30.f), 30.f);
    return 1.0f / (1.0f + __expf(-x));
}

__device__ __forceinline__ float fast_tanh(float x) {
    x = fminf(fmaxf(x, -15.f), 15.f);
    const float e = __expf(-2.0f * x);
    return (1.0f - e) / (1.0f + e);
}

// ---------------------------------------------------------------------------
// relayout_A: A f32 [8][1000][8000] -> Afrag bf16 in MFMA A-fragment order:
//   Afrag el = ((((b*2+h)*64 + mc)*125 + s)*64 + lane)*8 + j
//   holds A[b][i = mc*16 + (lane&15)][h*4000 + s*32 + (lane>>4)*8 + j]
// (rows i >= 1000 are clamped dup reads; big_mm discards those outputs.)
// grid 1280 = 16 tile x 5 kseg x 2 h x 8 b; block 256; LDS 64x133 f32.
// Global reads: 512B-contiguous row segments. Global writes: 1KB/wave-instr.
// ---------------------------------------------------------------------------
__global__ __launch_bounds__(256, 4) void relayout_A(
    const float* __restrict__ A, __bf16* __restrict__ Afrag)
{
    const int bx   = blockIdx.x;
    const int tile = bx & 15;
    const int rest = bx >> 4;
    const int kseg = rest % 5;
    const int rhb  = rest / 5;
    const int h    = rhb & 1;
    const int b    = rhb >> 1;

    const int t    = threadIdx.x;
    const int wv   = t >> 6;
    const int lane = t & 63;
    const int m    = lane & 15;
    const int q    = lane >> 4;

    __shared__ float L[64][133];   // +5 pad: b128 reads land 2-way max

    const float* Abase = A + (size_t)b * kN * 8000 + h * 4000;
    const int sbase = kseg * 25;   // 25 k-steps (800 floats) per block

    for (int kc = 0; kc < 800; kc += 128) {
        const int cw  = (kc < 768) ? 128 : 32;   // chunk width (floats)
        const int shl = (kc < 768) ? 5 : 3;      // log2(16B-chunks per row)
        const int rounds = (kc < 768) ? 8 : 2;
        const int kabs = kseg * 800 + kc;
        for (int p = 0; p < rounds; ++p) {
            const int idx = p * 256 + t;
            const int r   = idx >> shl;
            const int c4  = idx & ((cw >> 2) - 1);
            int i = tile * 64 + r;
            if (i >= kN) i = kN - 1;
            const float4 v = ld4(Abase + (size_t)i * 8000 + kabs + c4 * 4);
            *reinterpret_cast<float4*>(&L[r][c4 * 4]) = v;
        }
        __syncthreads();
        const int nst = cw >> 5;
        for (int sp = 0; sp < nst; ++sp) {
            const float4 a0 = *reinterpret_cast<const float4*>(&L[wv * 16 + m][sp * 32 + q * 8]);
            const float4 a1 = *reinterpret_cast<const float4*>(&L[wv * 16 + m][sp * 32 + q * 8 + 4]);
            const int s = sbase + (kc >> 5) + sp;
            const size_t el = ((((size_t)((b * 2 + h) * 64 + tile * 4 + wv)) * 125 + s) * 64 + lane) * 8;
            *reinterpret_cast<bf16x8_t*>(Afrag + el) = cvt8(a0, a1);
        }
        __syncthreads();
    }
}

// ---------------------------------------------------------------------------
// precompute_swt: SWTfrag in MFMA B-fragment order:
//   el = ((((b*2+h)*125 + s)*4 + c)*64 + lane)*8 + j
//   holds S[f = c*16 + (lane&15)][jg = s*32 + (lane>>4)*8 + j]
// where S[f][jg=e*1000+jj] = sum_d state[b][jj][d] * W[e][f][d].
// e-boundaries (1000) are multiples of 8, so every 16B octet is single-e.
// grid 1024 = 16 jt x 4 e x 2 h x 8 b; block 256.
// ---------------------------------------------------------------------------
__global__ __launch_bounds__(256) void precompute_swt(
    const float* __restrict__ state,   // [8000][64]
    const float* __restrict__ W_in,    // [4][64][64]
    const float* __restrict__ W_out,
    __bf16* __restrict__ SWTfrag)
{
    const int bx = blockIdx.x;
    const int jt = bx & 15;
    const int e  = (bx >> 4) & 3;
    const int h  = (bx >> 6) & 1;
    const int b  = bx >> 7;
    const float* W = (h ? W_out : W_in) + e * kD * kD;

    const int tid  = threadIdx.x;
    const int w    = tid >> 6;
    const int lane = tid & 63;
    const int m    = lane & 15;
    const int q    = lane >> 4;

    __shared__ __bf16 T[64][72];  // [f][j_local], +8 pad

    const int  jj    = jt * 64 + w * 16 + m;
    const bool valid = (jj < kN);
    const float* srow = state + ((size_t)b * kN + (valid ? jj : kN - 1)) * kD + q * 8;
    float4 a0 = ld4(srow),      a1 = ld4(srow + 4);
    float4 a2 = ld4(srow + 32), a3 = ld4(srow + 36);
    if (!valid) {
        a0 = make_float4(0.f, 0.f, 0.f, 0.f); a1 = a0; a2 = a0; a3 = a0;
    }
    const bf16x8_t af0 = cvt8(a0, a1);
    const bf16x8_t af1 = cvt8(a2, a3);

    #pragma unroll
    for (int c = 0; c < 4; ++c) {
        const int f = c * 16 + m;
        const float* wrow = W + f * kD + q * 8;
        const bf16x8_t bf0 = cvt8(ld4(wrow),      ld4(wrow + 4));
        const bf16x8_t bf1 = cvt8(ld4(wrow + 32), ld4(wrow + 36));
        f32x4_t acc = {0.f, 0.f, 0.f, 0.f};
        acc = MFMA16(af0, bf0, acc);
        acc = MFMA16(af1, bf1, acc);
        const int j0 = w * 16 + q * 4;
        bf16x4_t v;
        v[0] = (__bf16)acc[0]; v[1] = (__bf16)acc[1];
        v[2] = (__bf16)acc[2]; v[3] = (__bf16)acc[3];
        *reinterpret_cast<bf16x4_t*>(&T[f][j0]) = v;
    }
    __syncthreads();

    // frag-order writeout: 8 octets x 4 c x 16 m = 512 -> 2 rounds of 256
    const int bh = b * 2 + h;
    #pragma unroll
    for (int rep = 0; rep < 2; ++rep) {
        const int m2 = tid & 15;
        const int cc = (tid >> 4) & 3;
        const int ol = (tid >> 6) + rep * 4;
        const int j0 = jt * 64 + ol * 8;
        if (j0 < kN) {
            const int jg = e * kN + j0;
            const int s  = jg >> 5;
            const int qq = (jg >> 3) & 3;
            const uint4 v = *reinterpret_cast<uint4*>(&T[cc * 16 + m2][ol * 8]);
            const size_t el = ((((size_t)bh * 125 + s) * 4 + cc) * 64 + qq * 16 + m2) * 8;
            *reinterpret_cast<uint4*>((__bf16*)SWTfrag + el) = v;
        }
    }
}

// ---------------------------------------------------------------------------
// big_mm_f: a_half_p[ksp][b][i][f] = sum_{s in split} Afrag-step . SWTfrag-step
// grid 1024 = 16 tile x 2 h x 8 b x 4 ksp; block 256 (4 waves x 16 rows).
// LDS-free, barrier-free; per k-step 5 contiguous 1KB loads + 4 MFMA,
// depth-1 register prefetch. k-splits in steps: {32,32,32,29}.
// ---------------------------------------------------------------------------
__global__ __launch_bounds__(256, 4) void big_mm_f(
    const __bf16* __restrict__ Afrag,
    const __bf16* __restrict__ SWTfrag,
    float* __restrict__ a_in_p,        // [4][8000][64]
    float* __restrict__ a_out_p)
{
    const int bx   = blockIdx.x;
    const int tile = bx & 15;
    const int h    = (bx >> 4) & 1;
    const int b    = (bx >> 5) & 7;
    const int ksp  = bx >> 8;          // 0..3
    const int t    = threadIdx.x;
    const int wv   = t >> 6;
    const int lane = t & 63;
    const int m    = lane & 15;
    const int q    = lane >> 4;

    const int s0   = ksp * 32;
    const int send = (s0 + 32 < kSteps) ? s0 + 32 : kSteps;
    const int ns   = send - s0;        // 32 or 29

    const int bh = b * 2 + h;
    const __bf16* pA = Afrag +
        ((((size_t)(bh * 64 + tile * 4 + wv)) * 125 + s0) * 64 + lane) * 8;
    const __bf16* pB = SWTfrag +
        (((size_t)bh * 125 + s0) * 4 * 64) * 8 + (size_t)lane * 8;

    f32x4_t acc0 = {0.f, 0.f, 0.f, 0.f};
    f32x4_t acc1 = {0.f, 0.f, 0.f, 0.f};
    f32x4_t acc2 = {0.f, 0.f, 0.f, 0.f};
    f32x4_t acc3 = {0.f, 0.f, 0.f, 0.f};

    bf16x8_t cA  = *(const bf16x8_t*)(pA);
    bf16x8_t cB0 = *(const bf16x8_t*)(pB);
    bf16x8_t cB1 = *(const bf16x8_t*)(pB + 512);
    bf16x8_t cB2 = *(const bf16x8_t*)(pB + 1024);
    bf16x8_t cB3 = *(const bf16x8_t*)(pB + 1536);

    for (int s = 0; s < ns; ++s) {
        const int adv = (s + 1 < ns) ? 1 : 0;   // last iter: reload (unused)
        pA += adv * 512;
        pB += adv * 2048;
        const bf16x8_t nA  = *(const bf16x8_t*)(pA);
        const bf16x8_t nB0 = *(const bf16x8_t*)(pB);
        const bf16x8_t nB1 = *(const bf16x8_t*)(pB + 512);
        const bf16x8_t nB2 = *(const bf16x8_t*)(pB + 1024);
        const bf16x8_t nB3 = *(const bf16x8_t*)(pB + 1536);

        acc0 = MFMA16(cA, cB0, acc0);
        acc1 = MFMA16(cA, cB1, acc1);
        acc2 = MFMA16(cA, cB2, acc2);
        acc3 = MFMA16(cA, cB3, acc3);

        cA = nA; cB0 = nB0; cB1 = nB1; cB2 = nB2; cB3 = nB3;
    }

    float* dst = (h ? a_out_p : a_in_p) + (size_t)ksp * kP + (size_t)b * kN * kD;
    const int i0 = tile * 64 + wv * 16 + q * 4;
    #pragma unroll
    for (int r = 0; r < 4; ++r) {
        const int i = i0 + r;
        if (i < kN) {
            float* drow = dst + (size_t)i * kD + m;
            drow[0]  = acc0[r];
            drow[16] = acc1[r];
            drow[32] = acc2[r];
            drow[48] = acc3[r];
        }
    }
}

// ---------------------------------------------------------------------------
// Gating, col-split: block = 256 (4 waves), 16 rows per block, wave c owns
// output cols f = c*16..c*16+15. a_in/a_out = sum of 4 K-partials.
// step 1: write next state. step 2: fused output head.
// ---------------------------------------------------------------------------
__global__ __launch_bounds__(256, 2) void gating(
    const float* __restrict__ a_in_p,   // [4][8000][64]
    const float* __restrict__ a_out_p,
    const float* __restrict__ state,
    const float* __restrict__ W_r,
    const float* __restrict__ W_z,
    const float* __restrict__ W_h,
    float* __restrict__ s_next,
    const float* __restrict__ ann,
    const float* __restrict__ Wo1,
    const float* __restrict__ Wo2,
    float* __restrict__ out,
    const int step)
{
    const int i0   = blockIdx.x * 16;
    const int tid  = threadIdx.x;
    const int c    = tid >> 6;           // wave = column slice
    const int lane = tid & 63;
    const int m    = lane & 15;
    const int q    = lane >> 4;
    const int f    = c * 16 + m;

    __shared__ __bf16 TL[16][72];
    __shared__ float  Osum[4][16];

    const size_t rowA = (size_t)(i0 + m);

    bf16x8_t xf[6];
    {
        const float* p = a_in_p + rowA * kD + q * 8;
        xf[0] = sum4p(p);
        xf[1] = sum4p(p + 32);
        p = a_out_p + rowA * kD + q * 8;
        xf[2] = sum4p(p);
        xf[3] = sum4p(p + 32);
        p = state + rowA * kD + q * 8;
        xf[4] = cvt8(ld4(p),      ld4(p + 4));
        xf[5] = cvt8(ld4(p + 32), ld4(p + 36));
    }

    f32x4_t accr = {0.f, 0.f, 0.f, 0.f};
    f32x4_t accz = {0.f, 0.f, 0.f, 0.f};
    f32x4_t acch = {0.f, 0.f, 0.f, 0.f};

    const float* wr = W_r + f * 192 + q * 8;
    const float* wz = W_z + f * 192 + q * 8;
    const float* wh = W_h + f * 192 + q * 8;
    #pragma unroll
    for (int kc = 0; kc < 6; ++kc) {
        accr = MFMA16(xf[kc], cvt8(ld4(wr + kc * 32), ld4(wr + kc * 32 + 4)), accr);
        accz = MFMA16(xf[kc], cvt8(ld4(wz + kc * 32), ld4(wz + kc * 32 + 4)), accz);
        if (kc < 4)  // h-preact uses only [a_in|a_out] here (K=128)
            acch = MFMA16(xf[kc], cvt8(ld4(wh + kc * 32), ld4(wh + kc * 32 + 4)), acch);
    }

    float sC[4];
    #pragma unroll
    for (int r = 0; r < 4; ++r)
        sC[r] = state[(size_t)(i0 + q * 4 + r) * kD + f];

    // rs = sigm(r_pre) * state -> LDS transpose (C layout -> A layout)
    #pragma unroll
    for (int r = 0; r < 4; ++r)
        TL[q * 4 + r][f] = (__bf16)(sigm(accr[r]) * sC[r]);
    __syncthreads();
    const bf16x8_t rs0 = *(const bf16x8_t*)&TL[m][q * 8];
    const bf16x8_t rs1 = *(const bf16x8_t*)&TL[m][32 + q * 8];

    const float* wh3 = W_h + f * 192 + 128 + q * 8;
    acch = MFMA16(rs0, cvt8(ld4(wh3),      ld4(wh3 + 4)),  acch);
    acch = MFMA16(rs1, cvt8(ld4(wh3 + 32), ld4(wh3 + 36)), acch);

    float ns[4];
    #pragma unroll
    for (int r = 0; r < 4; ++r) {
        const float zv = sigm(accz[r]);
        ns[r] = (1.f - zv) * sC[r] + zv * fast_tanh(acch[r]);
    }

    if (step == 1) {
        #pragma unroll
        for (int r = 0; r < 4; ++r)
            s_next[(size_t)(i0 + q * 4 + r) * kD + f] = ns[r];
    } else {
        __syncthreads();  // all waves done reading rs frags from TL
        #pragma unroll
        for (int r = 0; r < 4; ++r)
            TL[q * 4 + r][f] = (__bf16)ns[r];
        __syncthreads();
        const bf16x8_t j0 = *(const bf16x8_t*)&TL[m][q * 8];
        const bf16x8_t j1 = *(const bf16x8_t*)&TL[m][32 + q * 8];
        const float* ap = ann + rowA * kAD + q * 8;
        const bf16x8_t j2 = cvt8(ld4(ap), ld4(ap + 4));

        f32x4_t acco = {0.f, 0.f, 0.f, 0.f};
        const float* wo = Wo1 + (size_t)f * 96 + q * 8;
        acco = MFMA16(j0, cvt8(ld4(wo),      ld4(wo + 4)),  acco);
        acco = MFMA16(j1, cvt8(ld4(wo + 32), ld4(wo + 36)), acco);
        acco = MFMA16(j2, cvt8(ld4(wo + 64), ld4(wo + 68)), acco);

        const float w2 = Wo2[f];
        float vs[4];
        #pragma unroll
        for (int r = 0; r < 4; ++r)
            vs[r] = fast_tanh(acco[r]) * w2;
        #pragma unroll
        for (int off = 1; off <= 8; off <<= 1) {
            #pragma unroll
            for (int r = 0; r < 4; ++r)
                vs[r] += __shfl_xor(vs[r], off, 64);
        }
        if (m == 0) {
            #pragma unroll
            for (int r = 0; r < 4; ++r)
                Osum[c][q * 4 + r] = vs[r];
        }
        __syncthreads();
        if (tid < 16)
            out[i0 + tid] = Osum[0][tid] + Osum[1][tid] + Osum[2][tid] + Osum[3][tid];
    }
}

extern "C" void kernel_launch(void* const* d_in, const int* in_sizes, int n_in,
                              void* d_out, int out_size, void* d_ws, size_t ws_size,
                              hipStream_t stream) {
    (void)in_sizes; (void)n_in; (void)out_size; (void)ws_size;

    const float* prop_state = (const float*)d_in[0];
    const float* annotation = (const float*)d_in[1];
    const float* A          = (const float*)d_in[2];
    const float* W_in       = (const float*)d_in[3];
    const float* W_out      = (const float*)d_in[4];
    const float* W_r        = (const float*)d_in[5];
    const float* W_z        = (const float*)d_in[6];
    const float* W_h        = (const float*)d_in[7];
    const float* Wo1        = (const float*)d_in[8];
    const float* Wo2        = (const float*)d_in[9];
    float* out = (float*)d_out;

    char* ws = (char*)d_ws;
    __bf16* Afrag   = (__bf16*)(ws);                    // 131,072,000 B
    __bf16* SWTfrag = (__bf16*)(ws + 131072000);        //   8,192,000 B
    float*  a_in_p  = (float*)(ws + 139264000);         //   8,192,000 B (4 planes)
    float*  a_out_p = (float*)(ws + 147456000);         //   8,192,000 B (4 planes)
    float*  s1      = (float*)(ws + 155648000);         //   2,048,000 B

    // one-time A relayout (covers both halves, both propagate steps)
    relayout_A<<<1280, 256, 0, stream>>>(A, Afrag);

    // step 1
    precompute_swt<<<1024, 256, 0, stream>>>(prop_state, W_in, W_out, SWTfrag);
    big_mm_f<<<1024, 256, 0, stream>>>(Afrag, SWTfrag, a_in_p, a_out_p);
    gating<<<500, 256, 0, stream>>>(a_in_p, a_out_p, prop_state, W_r, W_z, W_h,
                                    s1, nullptr, nullptr, nullptr, nullptr, 1);
    // step 2 (+ fused output head)
    precompute_swt<<<1024, 256, 0, stream>>>(s1, W_in, W_out, SWTfrag);
    big_mm_f<<<1024, 256, 0, stream>>>(Afrag, SWTfrag, a_in_p, a_out_p);
    gating<<<500, 256, 0, stream>>>(a_in_p, a_out_p, s1, W_r, W_z, W_h,
                                    nullptr, annotation, Wo1, Wo2, out, 2);
}